// Round 9
// baseline (181.408 us; speedup 1.0000x reference)
//
#include <hip/hip_runtime.h>
#include <hip/hip_fp16.h>

#define N_NODES 100000
#define N_EDGES 800000
#define N_BUCKET 391              // ceil(100000/256)
#define L_HIST (N_BUCKET * 256)   // 100096
#define DBINS 64
#define L_DH (DBINS * N_BUCKET)   // 25024
// D_IN=128, D_H=64, N_CLS=40, L=4, ALPHA=0.1, THETA=0.5
// State PRE-MULTIPLIED: h_pre = dinv*h, fp16, 128B/row, stored in DEGREE-SORTED (permuted) space.
// csr is relabeled to permuted ids; prop kernels are divergence-free (waves see ~equal degrees).

__device__ inline float4 f4zero() { return make_float4(0.f, 0.f, 0.f, 0.f); }

__device__ inline unsigned pack2u(float a, float b) {
    union { unsigned u; __half2 h; } r; r.h = __floats2half2_rn(a, b); return r.u;
}
__device__ inline float2 unpack2f(unsigned u) {
    union { unsigned uu; __half2 h; } d; d.uu = u; return __half22float2(d.h);
}

typedef _Float16 hf2 __attribute__((ext_vector_type(2)));
__device__ inline float fdot2(unsigned a, unsigned b, float c) {
#if __has_builtin(__builtin_amdgcn_fdot2)
    union { unsigned u; hf2 h; } ua, ub; ua.u = a; ub.u = b;
    return __builtin_amdgcn_fdot2(ua.h, ub.h, c, false);
#else
    float2 fa = unpack2f(a), fb = unpack2f(b);
    return fmaf(fa.x, fb.x, fmaf(fa.y, fb.y, c));
#endif
}

__device__ inline uint4 pack8(const float f[8]) {
    uint4 u;
    u.x = pack2u(f[0], f[1]); u.y = pack2u(f[2], f[3]);
    u.z = pack2u(f[4], f[5]); u.w = pack2u(f[6], f[7]);
    return u;
}
__device__ inline void unpack8(uint4 u, float f[8]) {
    float2 t;
    t = unpack2f(u.x); f[0] = t.x; f[1] = t.y;
    t = unpack2f(u.y); f[2] = t.x; f[3] = t.y;
    t = unpack2f(u.z); f[4] = t.x; f[5] = t.y;
    t = unpack2f(u.w); f[6] = t.x; f[7] = t.y;
}

// ---------------- CSR build via MSD bucket sort ----------------

__global__ __launch_bounds__(256) void k_hist(const int* __restrict__ col, int* __restrict__ histT) {
    __shared__ int hist[N_BUCKET];
    int b = blockIdx.x, t = threadIdx.x;
    for (int i = t; i < N_BUCKET; i += 256) hist[i] = 0;
    __syncthreads();
    const int base = b * 3125;
    for (int i = t; i < 3125; i += 256) atomicAdd(&hist[col[base + i] >> 8], 1);
    __syncthreads();
    for (int d = t; d < N_BUCKET; d += 256) histT[d * 256 + b] = hist[d];
}

// generic 3-kernel exclusive scan over L ints
__global__ __launch_bounds__(256) void k_scanA(const int* __restrict__ in, int* __restrict__ out,
                                               int* __restrict__ bsum, int L) {
    __shared__ int sh[256];
    int t = threadIdx.x, b = blockIdx.x;
    int base = b * 1024 + t * 4;
    int c0 = 0, c1 = 0, c2 = 0, c3 = 0;
    if (base + 3 < L) {
        int4 v = *reinterpret_cast<const int4*>(in + base);
        c0 = v.x; c1 = v.y; c2 = v.z; c3 = v.w;
    } else {
        if (base + 0 < L) c0 = in[base + 0];
        if (base + 1 < L) c1 = in[base + 1];
        if (base + 2 < L) c2 = in[base + 2];
    }
    int s = c0 + c1 + c2 + c3;
    sh[t] = s;
    __syncthreads();
    for (int off = 1; off < 256; off <<= 1) {
        int add = (t >= off) ? sh[t - off] : 0;
        __syncthreads();
        sh[t] += add;
        __syncthreads();
    }
    int excl = sh[t] - s;
    if (t == 255) bsum[b] = sh[t];
    int p = excl;
    if (base + 0 < L) out[base + 0] = p; p += c0;
    if (base + 1 < L) out[base + 1] = p; p += c1;
    if (base + 2 < L) out[base + 2] = p; p += c2;
    if (base + 3 < L) out[base + 3] = p;
}

__global__ __launch_bounds__(128) void k_scanB(int* __restrict__ bsum, int nb) {
    __shared__ int sh[128];
    int t = threadIdx.x;
    int v = (t < nb) ? bsum[t] : 0;
    sh[t] = v;
    __syncthreads();
    for (int off = 1; off < 128; off <<= 1) {
        int add = (t >= off) ? sh[t - off] : 0;
        __syncthreads();
        sh[t] += add;
        __syncthreads();
    }
    if (t < nb) bsum[t] = sh[t] - v;
}

__global__ __launch_bounds__(256) void k_scanC(int* __restrict__ out, const int* __restrict__ bsum, int L) {
    int t = threadIdx.x, b = blockIdx.x;
    int off = bsum[b];
    int base = b * 1024 + t * 4;
#pragma unroll
    for (int j = 0; j < 4; ++j)
        if (base + j < L) out[base + j] += off;
}

// pass-1 scatter into per-(digit,block) runs; packed elem = (col&255)<<17 | row
__global__ __launch_bounds__(256) void k_scatter1(const int* __restrict__ row, const int* __restrict__ col,
                                                  const int* __restrict__ hoff, unsigned* __restrict__ tmp) {
    __shared__ int lcnt[N_BUCKET];
    int b = blockIdx.x, t = threadIdx.x;
    for (int d = t; d < N_BUCKET; d += 256) lcnt[d] = hoff[d * 256 + b];
    __syncthreads();
    const int base = b * 3125;
    for (int i = t; i < 3125; i += 256) {
        int c = col[base + i];
        int r = row[base + i];
        int p = atomicAdd(&lcnt[c >> 8], 1);
        tmp[p] = ((unsigned)(c & 255) << 17) | (unsigned)r;
    }
}

// pass-2: counting sort within bucket; emits starts, deg, dinv, rsq (original node space)
__global__ __launch_bounds__(256) void k_bucket(const unsigned* __restrict__ tmp, const int* __restrict__ hoff,
                                                int* __restrict__ starts, int* __restrict__ csr,
                                                int* __restrict__ deg,
                                                float* __restrict__ dinv, float* __restrict__ rsq) {
    __shared__ int hist[256], sh[256], cur[256];
    int d = blockIdx.x, t = threadIdx.x;
    int s0 = hoff[d * 256];
    int s1 = (d < N_BUCKET - 1) ? hoff[(d + 1) * 256] : N_EDGES;
    int len = s1 - s0;
    hist[t] = 0;
    __syncthreads();
    for (int i = t; i < len; i += 256) atomicAdd(&hist[tmp[s0 + i] >> 17], 1);
    __syncthreads();
    int h = hist[t];
    sh[t] = h;
    __syncthreads();
    for (int off = 1; off < 256; off <<= 1) {
        int add = (t >= off) ? sh[t - off] : 0;
        __syncthreads();
        sh[t] += add;
        __syncthreads();
    }
    int excl = sh[t] - h;
    int colg = d * 256 + t;
    if (colg < N_NODES) {
        starts[colg] = s0 + excl;
        deg[colg] = h;
        dinv[colg] = rsqrtf((float)h + 1.f);
        rsq[colg]  = sqrtf((float)h + 1.f);
    }
    cur[t] = s0 + excl;
    __syncthreads();
    for (int i = t; i < len; i += 256) {
        unsigned e = tmp[s0 + i];
        int p = atomicAdd(&cur[e >> 17], 1);
        csr[p] = (int)(e & 0x1FFFFu);
    }
}

// ---------------- degree sort: histogram / scatter / metadata / relabel ----------------

__global__ __launch_bounds__(256) void k_dhist(const int* __restrict__ deg, int* __restrict__ dhT) {
    __shared__ int h[DBINS];
    int b = blockIdx.x, t = threadIdx.x;
    if (t < DBINS) h[t] = 0;
    __syncthreads();
    int i = b * 256 + t;
    if (i < N_NODES) atomicAdd(&h[min(deg[i], DBINS - 1)], 1);
    __syncthreads();
    if (t < DBINS) dhT[t * N_BUCKET + b] = h[t];
}

__global__ __launch_bounds__(256) void k_dscat(const int* __restrict__ deg, const int* __restrict__ dhoff,
                                               int* __restrict__ perm) {
    __shared__ int cur[DBINS];
    int b = blockIdx.x, t = threadIdx.x;
    if (t < DBINS) cur[t] = dhoff[t * N_BUCKET + b];
    __syncthreads();
    int i = b * 256 + t;
    if (i < N_NODES) {
        int p = atomicAdd(&cur[min(deg[i], DBINS - 1)], 1);
        perm[p] = i;
    }
}

// per-permuted-slot metadata + inverse permutation
__global__ __launch_bounds__(256) void k_pmeta(const int* __restrict__ perm, const int* __restrict__ starts,
                                               const int* __restrict__ deg, const float* __restrict__ dinv,
                                               const float* __restrict__ rsq,
                                               int* __restrict__ invp, int2* __restrict__ pse,
                                               float* __restrict__ pdinv, float* __restrict__ prsq) {
    int g = blockIdx.x * 256 + threadIdx.x;
    if (g >= N_NODES) return;
    int n = perm[g];
    invp[n] = g;
    pse[g] = make_int2(starts[n], deg[n]);
    pdinv[g] = dinv[n];
    prsq[g] = rsq[n];
}

// relabel csr into permuted space
__global__ __launch_bounds__(256) void k_relab(int* __restrict__ csr, const int* __restrict__ invp) {
    int i = blockIdx.x * 256 + threadIdx.x;
    if (i < N_EDGES) csr[i] = invp[csr[i]];
}

// ---------------- weight conversion: fp32 -> k-paired half2 ----------------
__global__ __launch_bounds__(256) void k_wcvt(const float* __restrict__ conv_w, const float* __restrict__ fc1_w,
                                              const float* __restrict__ fc0_w,
                                              unsigned* __restrict__ wh, unsigned* __restrict__ w1h,
                                              unsigned* __restrict__ w0h) {
    int i = blockIdx.x * 256 + threadIdx.x;
    if (i < 3 * 2048) {
        int layer = i >> 11, rem = i & 2047, kp = rem >> 6, c = rem & 63;
        const float* wsrc = conv_w + (size_t)(layer + 1) * 4096;
        wh[i] = pack2u(wsrc[(2 * kp) * 64 + c], wsrc[(2 * kp + 1) * 64 + c]);
        return;
    }
    int j = i - 3 * 2048;
    if (j < 1280) {
        int kp = j / 40, c = j - kp * 40;
        w1h[j] = pack2u(fc1_w[(2 * kp) * 40 + c], fc1_w[(2 * kp + 1) * 40 + c]);
        return;
    }
    int t = j - 1280;
    if (t < 4096) {
        int kp = t >> 6, c = t & 63;
        w0h[t] = pack2u(fc0_w[(2 * kp) * 64 + c], fc0_w[(2 * kp + 1) * 64 + c]);
    }
}

// ---------------- fc0: 128 -> 64 dot2; writes to PERMUTED slot invp[n] ----------------
__global__ __launch_bounds__(256, 4) void k_fc0(const float* __restrict__ x, const unsigned* __restrict__ w0h,
                                                const float* __restrict__ bias, const float* __restrict__ dinv,
                                                const int* __restrict__ invp, uint2* __restrict__ out) {
    __shared__ unsigned wsh[64 * 64];   // 16KB
    __shared__ unsigned xs2[64 * 65];   // 16.6KB, pad 65
    const float4* x4 = reinterpret_cast<const float4*>(x);
    int tid = threadIdx.x;
    int base = blockIdx.x * 64;
#pragma unroll
    for (int i = 0; i < 4; ++i)
        reinterpret_cast<uint4*>(wsh)[tid + 256 * i] = reinterpret_cast<const uint4*>(w0h)[tid + 256 * i];
#pragma unroll
    for (int j = 0; j < 8; ++j) {
        int f = tid + 256 * j;
        int ln = f >> 5, c = f & 31;
        float4 v = (base + ln < N_NODES) ? x4[(size_t)(base + ln) * 32 + c] : f4zero();
        xs2[ln * 65 + 2 * c]     = pack2u(v.x, v.y);
        xs2[ln * 65 + 2 * c + 1] = pack2u(v.z, v.w);
    }
    __syncthreads();
    int q = tid & 15, lbase = (tid >> 4) * 4;
    float4 bv = reinterpret_cast<const float4*>(bias)[q];
    float a[4][4];
#pragma unroll
    for (int n = 0; n < 4; ++n) { a[n][0] = bv.x; a[n][1] = bv.y; a[n][2] = bv.z; a[n][3] = bv.w; }
#pragma unroll 4
    for (int kp = 0; kp < 64; ++kp) {
        unsigned xh0 = xs2[(lbase + 0) * 65 + kp];
        unsigned xh1 = xs2[(lbase + 1) * 65 + kp];
        unsigned xh2 = xs2[(lbase + 2) * 65 + kp];
        unsigned xh3 = xs2[(lbase + 3) * 65 + kp];
        uint4 wv = *reinterpret_cast<const uint4*>(&wsh[kp * 64 + q * 4]);
        a[0][0] = fdot2(xh0, wv.x, a[0][0]); a[0][1] = fdot2(xh0, wv.y, a[0][1]);
        a[0][2] = fdot2(xh0, wv.z, a[0][2]); a[0][3] = fdot2(xh0, wv.w, a[0][3]);
        a[1][0] = fdot2(xh1, wv.x, a[1][0]); a[1][1] = fdot2(xh1, wv.y, a[1][1]);
        a[1][2] = fdot2(xh1, wv.z, a[1][2]); a[1][3] = fdot2(xh1, wv.w, a[1][3]);
        a[2][0] = fdot2(xh2, wv.x, a[2][0]); a[2][1] = fdot2(xh2, wv.y, a[2][1]);
        a[2][2] = fdot2(xh2, wv.z, a[2][2]); a[2][3] = fdot2(xh2, wv.w, a[2][3]);
        a[3][0] = fdot2(xh3, wv.x, a[3][0]); a[3][1] = fdot2(xh3, wv.y, a[3][1]);
        a[3][2] = fdot2(xh3, wv.z, a[3][2]); a[3][3] = fdot2(xh3, wv.w, a[3][3]);
    }
#pragma unroll
    for (int n = 0; n < 4; ++n) {
        int nn = base + lbase + n;
        if (nn < N_NODES) {
            float dc = dinv[nn];
            int pn = invp[nn];
            float r0 = dc * fmaxf(a[n][0], 0.f), r1 = dc * fmaxf(a[n][1], 0.f);
            float r2 = dc * fmaxf(a[n][2], 0.f), r3 = dc * fmaxf(a[n][3], 0.f);
            uint2 u; u.x = pack2u(r0, r1); u.y = pack2u(r2, r3);
            out[(size_t)pn * 16 + q] = u;
        }
    }
}

// ---------------- packed fp16 gather (4 pk_fma/edge) with csr prefetch ----------------
__device__ __forceinline__ void gather8h(const uint4* __restrict__ hp, const int* __restrict__ csr,
                                         int s, int e, int q, __half2 acc2[4]) {
    if (s >= e) return;
    int l = e - 1;
    int idx[8];
#pragma unroll
    for (int j = 0; j < 8; ++j) idx[j] = csr[min(s + j, l)];
    for (int p = s; p < e; p += 8) {
        uint4 d[8];
        unsigned msk[8];
#pragma unroll
        for (int j = 0; j < 8; ++j) {
            d[j] = hp[(size_t)idx[j] * 8 + q];
            msk[j] = (p + j <= l) ? 0x3C003C00u : 0u;  // half2{1,1} : {0,0}
        }
        if (p + 8 < e) {
#pragma unroll
            for (int j = 0; j < 8; ++j) idx[j] = csr[min(p + 8 + j, l)];
        }
#pragma unroll
        for (int j = 0; j < 8; ++j) {
            __half2 w2 = *reinterpret_cast<__half2*>(&msk[j]);
            const __half2* h2 = reinterpret_cast<const __half2*>(&d[j]);
            acc2[0] = __hfma2(w2, h2[0], acc2[0]);
            acc2[1] = __hfma2(w2, h2[1], acc2[1]);
            acc2[2] = __hfma2(w2, h2[2], acc2[2]);
            acc2[3] = __hfma2(w2, h2[3], acc2[3]);
        }
    }
}

// ---------------- prop0 (permuted space) ----------------
__global__ __launch_bounds__(256, 6) void k_prop0(const uint4* __restrict__ hp, uint4* __restrict__ x0p,
                                                  const float* __restrict__ pdinv,
                                                  const int2* __restrict__ pse, const int* __restrict__ csr) {
    int t = blockIdx.x * 256 + threadIdx.x;
    int g = t >> 3, q = t & 7;
    uint4 self = hp[(size_t)g * 8 + q];
    __half2 acc2[4];
    const __half2* sh2 = reinterpret_cast<const __half2*>(&self);
#pragma unroll
    for (int k = 0; k < 4; ++k) acc2[k] = sh2[k];
    int2 se = pse[g];
    gather8h(hp, csr, se.x, se.x + se.y, q, acc2);
    float dc = pdinv[g];
    float accf[8];
    unpack8(*reinterpret_cast<uint4*>(acc2), accf);
    float o[8];
#pragma unroll
    for (int k = 0; k < 8; ++k) o[k] = dc * fmaxf(dc * accf[k], 0.f);
    x0p[(size_t)g * 8 + q] = pack8(o);
}

// ---------------- fused: prop + alpha-combine + conv [+ fc1] (permuted space) ----------------
template <bool FINAL>
__global__ __launch_bounds__(256, 6) void k_propconv(
    const uint4* __restrict__ hp_in, const uint4* __restrict__ x0p,
    const float* __restrict__ pdinv, const float* __restrict__ prsq,
    const int2* __restrict__ pse, const int* __restrict__ csr,
    const int* __restrict__ perm,
    const unsigned* __restrict__ wh, float beta,
    const unsigned* __restrict__ w1h, const float* __restrict__ b1,
    void* __restrict__ out) {
    __shared__ unsigned ws2[32 * 64];                 // 8KB: paired conv W [kp][c]
    __shared__ unsigned ws12[FINAL ? 32 * 40 : 1];    // 5KB: paired fc1 W (FINAL)

    int tid = threadIdx.x;
    int nl = tid >> 3, q = tid & 7;
    int g = blockIdx.x * 32 + nl;

    // stage weights early (complete under the gather)
    reinterpret_cast<uint4*>(ws2)[tid]       = reinterpret_cast<const uint4*>(wh)[tid];
    reinterpret_cast<uint4*>(ws2)[tid + 256] = reinterpret_cast<const uint4*>(wh)[tid + 256];
    if constexpr (FINAL) {
        reinterpret_cast<uint4*>(ws12)[tid < 320 ? tid : 0] = reinterpret_cast<const uint4*>(w1h)[tid < 320 ? tid : 0];
        if (tid < 64) reinterpret_cast<uint4*>(ws12)[tid + 256] = reinterpret_cast<const uint4*>(w1h)[tid + 256];
    }

    uint4 self = hp_in[(size_t)g * 8 + q];
    __half2 acc2[4];
    const __half2* sh2 = reinterpret_cast<const __half2*>(&self);
#pragma unroll
    for (int k = 0; k < 4; ++k) acc2[k] = sh2[k];
    int2 se = pse[g];
    gather8h(hp_in, csr, se.x, se.x + se.y, q, acc2);

    float dc = pdinv[g];
    float rs = prsq[g];
    float accf[8], xq[8];
    unpack8(*reinterpret_cast<uint4*>(acc2), accf);
    unpack8(x0p[(size_t)g * 8 + q], xq);
    float m[8];
#pragma unroll
    for (int k = 0; k < 8; ++k) m[k] = 0.9f * dc * accf[k] + 0.1f * rs * xq[k];
    unsigned mh[4];
#pragma unroll
    for (int t = 0; t < 4; ++t) mh[t] = pack2u(m[2 * t], m[2 * t + 1]);

    __syncthreads();  // weights visible

    float a[8] = {0.f, 0.f, 0.f, 0.f, 0.f, 0.f, 0.f, 0.f};
#pragma unroll
    for (int src = 0; src < 8; ++src) {
        unsigned mm[4];
#pragma unroll
        for (int t = 0; t < 4; ++t) mm[t] = (unsigned)__shfl((int)mh[t], src, 8);
#pragma unroll
        for (int t = 0; t < 4; ++t) {
            int kp = src * 4 + t;
            const uint4* wr = reinterpret_cast<const uint4*>(&ws2[kp * 64 + q * 8]);
            uint4 w0 = wr[0], w1 = wr[1];
            a[0] = fdot2(mm[t], w0.x, a[0]); a[1] = fdot2(mm[t], w0.y, a[1]);
            a[2] = fdot2(mm[t], w0.z, a[2]); a[3] = fdot2(mm[t], w0.w, a[3]);
            a[4] = fdot2(mm[t], w1.x, a[4]); a[5] = fdot2(mm[t], w1.y, a[5]);
            a[6] = fdot2(mm[t], w1.z, a[6]); a[7] = fdot2(mm[t], w1.w, a[7]);
        }
    }
    float omb = 1.f - beta;
    float r[8];
#pragma unroll
    for (int k = 0; k < 8; ++k) r[k] = fmaxf(fmaf(omb, m[k], beta * a[k]), 0.f);

    if constexpr (!FINAL) {
        float o[8];
#pragma unroll
        for (int k = 0; k < 8; ++k) o[k] = dc * r[k];
        reinterpret_cast<uint4*>(out)[(size_t)g * 8 + q] = pack8(o);
    } else {
        unsigned rh[4];
#pragma unroll
        for (int t = 0; t < 4; ++t) rh[t] = pack2u(r[2 * t], r[2 * t + 1]);
        float acc1[5];
#pragma unroll
        for (int j = 0; j < 5; ++j) acc1[j] = b1[q * 5 + j];
#pragma unroll
        for (int src = 0; src < 8; ++src) {
            unsigned rm[4];
#pragma unroll
            for (int t = 0; t < 4; ++t) rm[t] = (unsigned)__shfl((int)rh[t], src, 8);
#pragma unroll
            for (int t = 0; t < 4; ++t) {
                int kp = src * 4 + t;
                const unsigned* wr = &ws12[kp * 40 + q * 5];
#pragma unroll
                for (int j = 0; j < 5; ++j) acc1[j] = fdot2(rm[t], wr[j], acc1[j]);
            }
        }
        int norig = perm[g];
        float* o = reinterpret_cast<float*>(out) + (size_t)norig * 40 + q * 5;
#pragma unroll
        for (int j = 0; j < 5; ++j) o[j] = acc1[j];
    }
}

// ---------------- launch ----------------

extern "C" void kernel_launch(void* const* d_in, const int* in_sizes, int n_in,
                              void* d_out, int out_size, void* d_ws, size_t ws_size,
                              hipStream_t stream) {
    const float* x      = (const float*)d_in[0];
    const int*   ei     = (const int*)d_in[1];
    const float* fc0_w  = (const float*)d_in[2];
    const float* fc0_b  = (const float*)d_in[3];
    const float* fc1_w  = (const float*)d_in[4];
    const float* fc1_b  = (const float*)d_in[5];
    const float* conv_w = (const float*)d_in[6];
    const int* row = ei;
    const int* col = ei + N_EDGES;

    char* ws = (char*)d_ws;
    size_t off = 0;
    auto alloc = [&](size_t bytes) -> void* {
        void* p = ws + off;
        off += (bytes + 255) & ~(size_t)255;
        return p;
    };
    float*    dinv   = (float*)alloc((size_t)N_NODES * 4);
    float*    rsq    = (float*)alloc((size_t)N_NODES * 4);
    int*      starts = (int*)alloc((size_t)N_NODES * 4);
    int*      deg    = (int*)alloc((size_t)N_NODES * 4);
    int*      histT  = (int*)alloc((size_t)L_HIST * 4);
    int*      hoff   = (int*)alloc((size_t)L_HIST * 4);
    int*      bsumA  = (int*)alloc(128 * 4);
    int*      bsumB  = (int*)alloc(128 * 4);
    unsigned* tmp    = (unsigned*)alloc((size_t)N_EDGES * 4);
    int*      csr    = (int*)alloc((size_t)N_EDGES * 4);
    int*      dhT    = (int*)alloc((size_t)L_DH * 4);
    int*      dhoff  = (int*)alloc((size_t)L_DH * 4);
    int*      perm   = (int*)alloc((size_t)N_NODES * 4);
    int*      invp   = (int*)alloc((size_t)N_NODES * 4);
    int2*     pse    = (int2*)alloc((size_t)N_NODES * 8);
    float*    pdinv  = (float*)alloc((size_t)N_NODES * 4);
    float*    prsq   = (float*)alloc((size_t)N_NODES * 4);
    unsigned* wh     = (unsigned*)alloc(3 * 2048 * 4);
    unsigned* w1h    = (unsigned*)alloc(1280 * 4);
    unsigned* w0h    = (unsigned*)alloc(4096 * 4);
    uint4*    hp0    = (uint4*)alloc((size_t)N_NODES * 128);
    uint4*    x0p    = (uint4*)alloc((size_t)N_NODES * 128);
    uint4*    hpA    = (uint4*)alloc((size_t)N_NODES * 128);
    uint4*    hpB    = (uint4*)alloc((size_t)N_NODES * 128);
    if (off > ws_size) return;

    const int NBH  = (L_HIST + 1023) / 1024;          // 98
    const int NBD  = (L_DH + 1023) / 1024;            // 25
    const int GMM  = (N_NODES + 63) / 64;             // 1563 (fc0)
    const int GP   = (N_NODES * 8) / 256;             // 3125 (prop0)
    const int GPC  = N_NODES / 32;                    // 3125 (propconv)

    // weight conversion + CSR bucket-sort build
    k_wcvt<<<45, 256, 0, stream>>>(conv_w, fc1_w, fc0_w, wh, w1h, w0h);
    k_hist<<<256, 256, 0, stream>>>(col, histT);
    k_scanA<<<NBH, 256, 0, stream>>>(histT, hoff, bsumA, L_HIST);
    k_scanB<<<1, 128, 0, stream>>>(bsumA, NBH);
    k_scanC<<<NBH, 256, 0, stream>>>(hoff, bsumA, L_HIST);
    k_scatter1<<<256, 256, 0, stream>>>(row, col, hoff, tmp);
    k_bucket<<<N_BUCKET, 256, 0, stream>>>(tmp, hoff, starts, csr, deg, dinv, rsq);

    // degree sort + permuted metadata + csr relabel
    k_dhist<<<N_BUCKET, 256, 0, stream>>>(deg, dhT);
    k_scanA<<<NBD, 256, 0, stream>>>(dhT, dhoff, bsumB, L_DH);
    k_scanB<<<1, 128, 0, stream>>>(bsumB, NBD);
    k_scanC<<<NBD, 256, 0, stream>>>(dhoff, bsumB, L_DH);
    k_dscat<<<N_BUCKET, 256, 0, stream>>>(deg, dhoff, perm);
    k_pmeta<<<N_BUCKET, 256, 0, stream>>>(perm, starts, deg, dinv, rsq, invp, pse, pdinv, prsq);
    k_relab<<<(N_EDGES + 255) / 256, 256, 0, stream>>>(csr, invp);

    // fc0 -> hp0 (permuted); prop0 -> x0p
    k_fc0<<<GMM, 256, 0, stream>>>(x, w0h, fc0_b, dinv, invp, (uint2*)hp0);
    k_prop0<<<GP, 256, 0, stream>>>(hp0, x0p, pdinv, pse, csr);

    const float betas[4] = {0.f, logf(0.5f / 2.f + 1.f), logf(0.5f / 3.f + 1.f), logf(0.5f / 4.f + 1.f)};

    // layer 1: x0p -> hpA ; layer 2: hpA -> hpB ; layer 3 (+fc1): hpB -> d_out
    k_propconv<false><<<GPC, 256, 0, stream>>>(x0p, x0p, pdinv, prsq, pse, csr, perm,
                                               wh + 0 * 2048, betas[1], nullptr, nullptr, hpA);
    k_propconv<false><<<GPC, 256, 0, stream>>>(hpA, x0p, pdinv, prsq, pse, csr, perm,
                                               wh + 1 * 2048, betas[2], nullptr, nullptr, hpB);
    k_propconv<true><<<GPC, 256, 0, stream>>>(hpB, x0p, pdinv, prsq, pse, csr, perm,
                                              wh + 2 * 2048, betas[3], w1h, fc1_b, d_out);
}

// Round 10
// 157.980 us; speedup vs baseline: 1.1483x; 1.1483x over previous
//
#include <hip/hip_runtime.h>
#include <hip/hip_fp16.h>

#define N_NODES 100000
#define N_EDGES 800000
#define N_BUCKET 391              // ceil(100000/256)
#define L_HIST (N_BUCKET * 256)   // 100096
// D_IN=128, D_H=64, N_CLS=40, L=4, ALPHA=0.1, THETA=0.5
// State PRE-MULTIPLIED: h_pre[n] = dinv[n]*h[n], fp16 (64 halves = 128B/row).
// prop(h)[c] = dinv[c] * (h_pre[c] + sum_src h_pre[src]) — unweighted gather, int CSR.
// CSR built via MSD bucket sort (col>>8 then col&255) — clustered writes, no scattered 4B stores.
// NOTE (r9 lesson): degree-sorted relabeling was tried and REGRESSED — the gather is
// memory-system-bound (~3.4 TB/s effective on random 128B reads), not divergence-bound.

__device__ inline float4 f4zero() { return make_float4(0.f, 0.f, 0.f, 0.f); }

__device__ inline unsigned pack2u(float a, float b) {
    union { unsigned u; __half2 h; } r; r.h = __floats2half2_rn(a, b); return r.u;
}
__device__ inline float2 unpack2f(unsigned u) {
    union { unsigned uu; __half2 h; } d; d.uu = u; return __half22float2(d.h);
}

typedef _Float16 hf2 __attribute__((ext_vector_type(2)));
__device__ inline float fdot2(unsigned a, unsigned b, float c) {
#if __has_builtin(__builtin_amdgcn_fdot2)
    union { unsigned u; hf2 h; } ua, ub; ua.u = a; ub.u = b;
    return __builtin_amdgcn_fdot2(ua.h, ub.h, c, false);
#else
    float2 fa = unpack2f(a), fb = unpack2f(b);
    return fmaf(fa.x, fb.x, fmaf(fa.y, fb.y, c));
#endif
}

__device__ inline uint4 pack8(const float f[8]) {
    uint4 u;
    u.x = pack2u(f[0], f[1]); u.y = pack2u(f[2], f[3]);
    u.z = pack2u(f[4], f[5]); u.w = pack2u(f[6], f[7]);
    return u;
}
__device__ inline void unpack8(uint4 u, float f[8]) {
    float2 t;
    t = unpack2f(u.x); f[0] = t.x; f[1] = t.y;
    t = unpack2f(u.y); f[2] = t.x; f[3] = t.y;
    t = unpack2f(u.z); f[4] = t.x; f[5] = t.y;
    t = unpack2f(u.w); f[6] = t.x; f[7] = t.y;
}

// ---------------- CSR build via MSD bucket sort ----------------

// pass-1 histogram: 256 blocks x 3125 edges; transposed output histT[d*256 + b]
__global__ __launch_bounds__(256) void k_hist(const int* __restrict__ col, int* __restrict__ histT) {
    __shared__ int hist[N_BUCKET];
    int b = blockIdx.x, t = threadIdx.x;
    for (int i = t; i < N_BUCKET; i += 256) hist[i] = 0;
    __syncthreads();
    const int base = b * 3125;
    for (int i = t; i < 3125; i += 256) atomicAdd(&hist[col[base + i] >> 8], 1);
    __syncthreads();
    for (int d = t; d < N_BUCKET; d += 256) histT[d * 256 + b] = hist[d];
}

// generic 3-kernel exclusive scan over L ints (L = 100096 here)
__global__ __launch_bounds__(256) void k_scanA(const int* __restrict__ in, int* __restrict__ out,
                                               int* __restrict__ bsum, int L) {
    __shared__ int sh[256];
    int t = threadIdx.x, b = blockIdx.x;
    int base = b * 1024 + t * 4;
    int c0 = 0, c1 = 0, c2 = 0, c3 = 0;
    if (base + 3 < L) {
        int4 v = *reinterpret_cast<const int4*>(in + base);
        c0 = v.x; c1 = v.y; c2 = v.z; c3 = v.w;
    } else {
        if (base + 0 < L) c0 = in[base + 0];
        if (base + 1 < L) c1 = in[base + 1];
        if (base + 2 < L) c2 = in[base + 2];
    }
    int s = c0 + c1 + c2 + c3;
    sh[t] = s;
    __syncthreads();
    for (int off = 1; off < 256; off <<= 1) {
        int add = (t >= off) ? sh[t - off] : 0;
        __syncthreads();
        sh[t] += add;
        __syncthreads();
    }
    int excl = sh[t] - s;
    if (t == 255) bsum[b] = sh[t];
    int p = excl;
    if (base + 0 < L) out[base + 0] = p; p += c0;
    if (base + 1 < L) out[base + 1] = p; p += c1;
    if (base + 2 < L) out[base + 2] = p; p += c2;
    if (base + 3 < L) out[base + 3] = p;
}

__global__ __launch_bounds__(128) void k_scanB(int* __restrict__ bsum, int nb) {
    __shared__ int sh[128];
    int t = threadIdx.x;
    int v = (t < nb) ? bsum[t] : 0;
    sh[t] = v;
    __syncthreads();
    for (int off = 1; off < 128; off <<= 1) {
        int add = (t >= off) ? sh[t - off] : 0;
        __syncthreads();
        sh[t] += add;
        __syncthreads();
    }
    if (t < nb) bsum[t] = sh[t] - v;
}

__global__ __launch_bounds__(256) void k_scanC(int* __restrict__ out, const int* __restrict__ bsum, int L) {
    int t = threadIdx.x, b = blockIdx.x;
    int off = bsum[b];
    int base = b * 1024 + t * 4;
#pragma unroll
    for (int j = 0; j < 4; ++j)
        if (base + j < L) out[base + j] += off;
}

// pass-1 scatter: block b writes its edges into its private per-digit runs
// packed elem = (col&255)<<17 | row   (row < 2^17)
__global__ __launch_bounds__(256) void k_scatter1(const int* __restrict__ row, const int* __restrict__ col,
                                                  const int* __restrict__ hoff, unsigned* __restrict__ tmp) {
    __shared__ int lcnt[N_BUCKET];
    int b = blockIdx.x, t = threadIdx.x;
    for (int d = t; d < N_BUCKET; d += 256) lcnt[d] = hoff[d * 256 + b];
    __syncthreads();
    const int base = b * 3125;
    for (int i = t; i < 3125; i += 256) {
        int c = col[base + i];
        int r = row[base + i];
        int p = atomicAdd(&lcnt[c >> 8], 1);
        tmp[p] = ((unsigned)(c & 255) << 17) | (unsigned)r;
    }
}

// pass-2: one block per bucket — counting sort by low 8 bits entirely from a contiguous segment.
// Also emits starts, dinv, rsq (per-col counts are the histogram).
__global__ __launch_bounds__(256) void k_bucket(const unsigned* __restrict__ tmp, const int* __restrict__ hoff,
                                                int* __restrict__ starts, int* __restrict__ csr,
                                                float* __restrict__ dinv, float* __restrict__ rsq) {
    __shared__ int hist[256], sh[256], cur[256];
    int d = blockIdx.x, t = threadIdx.x;
    int s0 = hoff[d * 256];
    int s1 = (d < N_BUCKET - 1) ? hoff[(d + 1) * 256] : N_EDGES;
    int len = s1 - s0;
    hist[t] = 0;
    __syncthreads();
    for (int i = t; i < len; i += 256) atomicAdd(&hist[tmp[s0 + i] >> 17], 1);
    __syncthreads();
    int h = hist[t];
    sh[t] = h;
    __syncthreads();
    for (int off = 1; off < 256; off <<= 1) {
        int add = (t >= off) ? sh[t - off] : 0;
        __syncthreads();
        sh[t] += add;
        __syncthreads();
    }
    int excl = sh[t] - h;
    int colg = d * 256 + t;
    if (colg < N_NODES) {
        starts[colg] = s0 + excl;
        dinv[colg] = rsqrtf((float)h + 1.f);
        rsq[colg]  = sqrtf((float)h + 1.f);
    }
    if (d == N_BUCKET - 1 && t == 0) starts[N_NODES] = N_EDGES;
    cur[t] = s0 + excl;
    __syncthreads();
    for (int i = t; i < len; i += 256) {
        unsigned e = tmp[s0 + i];
        int p = atomicAdd(&cur[e >> 17], 1);
        csr[p] = (int)(e & 0x1FFFFu);
    }
}

// ---------------- weight conversion: fp32 -> k-paired half2 ----------------
__global__ __launch_bounds__(256) void k_wcvt(const float* __restrict__ conv_w, const float* __restrict__ fc1_w,
                                              const float* __restrict__ fc0_w,
                                              unsigned* __restrict__ wh, unsigned* __restrict__ w1h,
                                              unsigned* __restrict__ w0h) {
    int i = blockIdx.x * 256 + threadIdx.x;
    if (i < 3 * 2048) {
        int layer = i >> 11, rem = i & 2047, kp = rem >> 6, c = rem & 63;
        const float* wsrc = conv_w + (size_t)(layer + 1) * 4096;
        wh[i] = pack2u(wsrc[(2 * kp) * 64 + c], wsrc[(2 * kp + 1) * 64 + c]);
        return;
    }
    int j = i - 3 * 2048;
    if (j < 1280) {
        int kp = j / 40, c = j - kp * 40;
        w1h[j] = pack2u(fc1_w[(2 * kp) * 40 + c], fc1_w[(2 * kp + 1) * 40 + c]);
        return;
    }
    int t = j - 1280;
    if (t < 4096) {
        int kp = t >> 6, c = t & 63;
        w0h[t] = pack2u(fc0_w[(2 * kp) * 64 + c], fc0_w[(2 * kp + 1) * 64 + c]);
    }
}

// ---------------- fc0: h_pre0 = fp16(dinv * relu(x @ W0 + b0)), 128 -> 64, dot2 ----------------
__global__ __launch_bounds__(256, 4) void k_fc0(const float* __restrict__ x, const unsigned* __restrict__ w0h,
                                                const float* __restrict__ bias, const float* __restrict__ dinv,
                                                uint2* __restrict__ out) {
    __shared__ unsigned wsh[64 * 64];   // 16KB
    __shared__ unsigned xs2[64 * 65];   // 16.6KB, pad 65
    const float4* x4 = reinterpret_cast<const float4*>(x);
    int tid = threadIdx.x;
    int base = blockIdx.x * 64;
#pragma unroll
    for (int i = 0; i < 4; ++i)
        reinterpret_cast<uint4*>(wsh)[tid + 256 * i] = reinterpret_cast<const uint4*>(w0h)[tid + 256 * i];
#pragma unroll
    for (int j = 0; j < 8; ++j) {
        int f = tid + 256 * j;          // 0..2047
        int ln = f >> 5, c = f & 31;    // c-th float4 of row ln
        float4 v = (base + ln < N_NODES) ? x4[(size_t)(base + ln) * 32 + c] : f4zero();
        xs2[ln * 65 + 2 * c]     = pack2u(v.x, v.y);
        xs2[ln * 65 + 2 * c + 1] = pack2u(v.z, v.w);
    }
    __syncthreads();
    int q = tid & 15, lbase = (tid >> 4) * 4;
    float4 bv = reinterpret_cast<const float4*>(bias)[q];
    float a[4][4];
#pragma unroll
    for (int n = 0; n < 4; ++n) { a[n][0] = bv.x; a[n][1] = bv.y; a[n][2] = bv.z; a[n][3] = bv.w; }
#pragma unroll 4
    for (int kp = 0; kp < 64; ++kp) {
        unsigned xh0 = xs2[(lbase + 0) * 65 + kp];
        unsigned xh1 = xs2[(lbase + 1) * 65 + kp];
        unsigned xh2 = xs2[(lbase + 2) * 65 + kp];
        unsigned xh3 = xs2[(lbase + 3) * 65 + kp];
        uint4 wv = *reinterpret_cast<const uint4*>(&wsh[kp * 64 + q * 4]);
        a[0][0] = fdot2(xh0, wv.x, a[0][0]); a[0][1] = fdot2(xh0, wv.y, a[0][1]);
        a[0][2] = fdot2(xh0, wv.z, a[0][2]); a[0][3] = fdot2(xh0, wv.w, a[0][3]);
        a[1][0] = fdot2(xh1, wv.x, a[1][0]); a[1][1] = fdot2(xh1, wv.y, a[1][1]);
        a[1][2] = fdot2(xh1, wv.z, a[1][2]); a[1][3] = fdot2(xh1, wv.w, a[1][3]);
        a[2][0] = fdot2(xh2, wv.x, a[2][0]); a[2][1] = fdot2(xh2, wv.y, a[2][1]);
        a[2][2] = fdot2(xh2, wv.z, a[2][2]); a[2][3] = fdot2(xh2, wv.w, a[2][3]);
        a[3][0] = fdot2(xh3, wv.x, a[3][0]); a[3][1] = fdot2(xh3, wv.y, a[3][1]);
        a[3][2] = fdot2(xh3, wv.z, a[3][2]); a[3][3] = fdot2(xh3, wv.w, a[3][3]);
    }
#pragma unroll
    for (int n = 0; n < 4; ++n) {
        int nn = base + lbase + n;
        if (nn < N_NODES) {
            float dc = dinv[nn];
            float r0 = dc * fmaxf(a[n][0], 0.f), r1 = dc * fmaxf(a[n][1], 0.f);
            float r2 = dc * fmaxf(a[n][2], 0.f), r3 = dc * fmaxf(a[n][3], 0.f);
            uint2 u; u.x = pack2u(r0, r1); u.y = pack2u(r2, r3);
            out[(size_t)nn * 16 + q] = u;
        }
    }
}

// ---------------- packed fp16 gather (4 pk_fma/edge) with csr prefetch ----------------
__device__ __forceinline__ void gather8h(const uint4* __restrict__ hp, const int* __restrict__ csr,
                                         int s, int e, int q, __half2 acc2[4]) {
    if (s >= e) return;
    int l = e - 1;
    int idx[8];
#pragma unroll
    for (int j = 0; j < 8; ++j) idx[j] = csr[min(s + j, l)];
    for (int p = s; p < e; p += 8) {
        uint4 d[8];
        unsigned msk[8];
#pragma unroll
        for (int j = 0; j < 8; ++j) {
            d[j] = hp[(size_t)idx[j] * 8 + q];
            msk[j] = (p + j <= l) ? 0x3C003C00u : 0u;  // half2{1,1} : {0,0}
        }
        if (p + 8 < e) {
#pragma unroll
            for (int j = 0; j < 8; ++j) idx[j] = csr[min(p + 8 + j, l)];
        }
#pragma unroll
        for (int j = 0; j < 8; ++j) {
            __half2 w2 = *reinterpret_cast<__half2*>(&msk[j]);
            const __half2* h2 = reinterpret_cast<const __half2*>(&d[j]);
            acc2[0] = __hfma2(w2, h2[0], acc2[0]);
            acc2[1] = __hfma2(w2, h2[1], acc2[1]);
            acc2[2] = __hfma2(w2, h2[2], acc2[2]);
            acc2[3] = __hfma2(w2, h2[3], acc2[3]);
        }
    }
}

// ---------------- prop0 ----------------
__global__ __launch_bounds__(256, 6) void k_prop0(const uint4* __restrict__ hp, uint4* __restrict__ x0p,
                                                  const float* __restrict__ dinv,
                                                  const int* __restrict__ starts, const int* __restrict__ csr) {
    int t = blockIdx.x * 256 + threadIdx.x;
    int node = t >> 3, q = t & 7;
    uint4 self = hp[(size_t)node * 8 + q];
    __half2 acc2[4];
    const __half2* sh2 = reinterpret_cast<const __half2*>(&self);
#pragma unroll
    for (int k = 0; k < 4; ++k) acc2[k] = sh2[k];
    gather8h(hp, csr, starts[node], starts[node + 1], q, acc2);
    float dc = dinv[node];
    float accf[8];
    unpack8(*reinterpret_cast<uint4*>(acc2), accf);
    float o[8];
#pragma unroll
    for (int k = 0; k < 8; ++k) o[k] = dc * fmaxf(dc * accf[k], 0.f);
    x0p[(size_t)node * 8 + q] = pack8(o);
}

// ---------------- fused: prop + alpha-combine + conv [+ fc1], all dot2 ----------------
template <bool FINAL>
__global__ __launch_bounds__(256, 6) void k_propconv(
    const uint4* __restrict__ hp_in, const uint4* __restrict__ x0p,
    const float* __restrict__ dinv, const float* __restrict__ rsq,
    const int* __restrict__ starts, const int* __restrict__ csr,
    const unsigned* __restrict__ wh, float beta,
    const unsigned* __restrict__ w1h, const float* __restrict__ b1,
    void* __restrict__ out) {
    __shared__ unsigned ws2[32 * 64];                 // 8KB: paired conv W [kp][c]
    __shared__ unsigned ws12[FINAL ? 32 * 40 : 1];    // 5KB: paired fc1 W (FINAL)

    int tid = threadIdx.x;
    int nl = tid >> 3, q = tid & 7;
    int node = blockIdx.x * 32 + nl;

    // stage weights early (complete under the gather)
    reinterpret_cast<uint4*>(ws2)[tid]       = reinterpret_cast<const uint4*>(wh)[tid];
    reinterpret_cast<uint4*>(ws2)[tid + 256] = reinterpret_cast<const uint4*>(wh)[tid + 256];
    if constexpr (FINAL) {
        reinterpret_cast<uint4*>(ws12)[tid < 320 ? tid : 0] = reinterpret_cast<const uint4*>(w1h)[tid < 320 ? tid : 0];
        if (tid < 64) reinterpret_cast<uint4*>(ws12)[tid + 256] = reinterpret_cast<const uint4*>(w1h)[tid + 256];
    }

    uint4 self = hp_in[(size_t)node * 8 + q];
    __half2 acc2[4];
    const __half2* sh2 = reinterpret_cast<const __half2*>(&self);
#pragma unroll
    for (int k = 0; k < 4; ++k) acc2[k] = sh2[k];
    gather8h(hp_in, csr, starts[node], starts[node + 1], q, acc2);

    float dc = dinv[node];
    float rs = rsq[node];
    float accf[8], xq[8];
    unpack8(*reinterpret_cast<uint4*>(acc2), accf);
    unpack8(x0p[(size_t)node * 8 + q], xq);
    float m[8];
#pragma unroll
    for (int k = 0; k < 8; ++k) m[k] = 0.9f * dc * accf[k] + 0.1f * rs * xq[k];
    unsigned mh[4];
#pragma unroll
    for (int t = 0; t < 4; ++t) mh[t] = pack2u(m[2 * t], m[2 * t + 1]);

    __syncthreads();  // weights visible

    // conv: a[c] = sum_k m[k]*W[k][c] via dot2; m fetched from owner lane via shfl(width 8)
    float a[8] = {0.f, 0.f, 0.f, 0.f, 0.f, 0.f, 0.f, 0.f};
#pragma unroll
    for (int src = 0; src < 8; ++src) {
        unsigned mm[4];
#pragma unroll
        for (int t = 0; t < 4; ++t) mm[t] = (unsigned)__shfl((int)mh[t], src, 8);
#pragma unroll
        for (int t = 0; t < 4; ++t) {
            int kp = src * 4 + t;
            const uint4* wr = reinterpret_cast<const uint4*>(&ws2[kp * 64 + q * 8]);
            uint4 w0 = wr[0], w1 = wr[1];
            a[0] = fdot2(mm[t], w0.x, a[0]); a[1] = fdot2(mm[t], w0.y, a[1]);
            a[2] = fdot2(mm[t], w0.z, a[2]); a[3] = fdot2(mm[t], w0.w, a[3]);
            a[4] = fdot2(mm[t], w1.x, a[4]); a[5] = fdot2(mm[t], w1.y, a[5]);
            a[6] = fdot2(mm[t], w1.z, a[6]); a[7] = fdot2(mm[t], w1.w, a[7]);
        }
    }
    float omb = 1.f - beta;
    float r[8];
#pragma unroll
    for (int k = 0; k < 8; ++k) r[k] = fmaxf(fmaf(omb, m[k], beta * a[k]), 0.f);

    if constexpr (!FINAL) {
        float o[8];
#pragma unroll
        for (int k = 0; k < 8; ++k) o[k] = dc * r[k];
        reinterpret_cast<uint4*>(out)[(size_t)node * 8 + q] = pack8(o);
    } else {
        // fc1 via the same shuffle+dot2 trick (no LDS tile)
        unsigned rh[4];
#pragma unroll
        for (int t = 0; t < 4; ++t) rh[t] = pack2u(r[2 * t], r[2 * t + 1]);
        float acc1[5];
#pragma unroll
        for (int j = 0; j < 5; ++j) acc1[j] = b1[q * 5 + j];
#pragma unroll
        for (int src = 0; src < 8; ++src) {
            unsigned rm[4];
#pragma unroll
            for (int t = 0; t < 4; ++t) rm[t] = (unsigned)__shfl((int)rh[t], src, 8);
#pragma unroll
            for (int t = 0; t < 4; ++t) {
                int kp = src * 4 + t;
                const unsigned* wr = &ws12[kp * 40 + q * 5];
#pragma unroll
                for (int j = 0; j < 5; ++j) acc1[j] = fdot2(rm[t], wr[j], acc1[j]);
            }
        }
        float* o = reinterpret_cast<float*>(out) + (size_t)node * 40 + q * 5;
#pragma unroll
        for (int j = 0; j < 5; ++j) o[j] = acc1[j];
    }
}

// ---------------- launch ----------------

extern "C" void kernel_launch(void* const* d_in, const int* in_sizes, int n_in,
                              void* d_out, int out_size, void* d_ws, size_t ws_size,
                              hipStream_t stream) {
    const float* x      = (const float*)d_in[0];
    const int*   ei     = (const int*)d_in[1];
    const float* fc0_w  = (const float*)d_in[2];
    const float* fc0_b  = (const float*)d_in[3];
    const float* fc1_w  = (const float*)d_in[4];
    const float* fc1_b  = (const float*)d_in[5];
    const float* conv_w = (const float*)d_in[6];
    const int* row = ei;
    const int* col = ei + N_EDGES;

    char* ws = (char*)d_ws;
    size_t off = 0;
    auto alloc = [&](size_t bytes) -> void* {
        void* p = ws + off;
        off += (bytes + 255) & ~(size_t)255;
        return p;
    };
    float*    dinv   = (float*)alloc((size_t)N_NODES * 4);
    float*    rsq    = (float*)alloc((size_t)N_NODES * 4);
    int*      starts = (int*)alloc((size_t)(N_NODES + 1) * 4);
    int*      histT  = (int*)alloc((size_t)L_HIST * 4);
    int*      hoff   = (int*)alloc((size_t)L_HIST * 4);
    int*      bsum   = (int*)alloc(128 * 4);
    unsigned* tmp    = (unsigned*)alloc((size_t)N_EDGES * 4);
    int*      csr    = (int*)alloc((size_t)N_EDGES * 4);
    unsigned* wh     = (unsigned*)alloc(3 * 2048 * 4);
    unsigned* w1h    = (unsigned*)alloc(1280 * 4);
    unsigned* w0h    = (unsigned*)alloc(4096 * 4);
    uint4*    hp0    = (uint4*)alloc((size_t)N_NODES * 128);
    uint4*    x0p    = (uint4*)alloc((size_t)N_NODES * 128);
    uint4*    hpA    = (uint4*)alloc((size_t)N_NODES * 128);
    uint4*    hpB    = (uint4*)alloc((size_t)N_NODES * 128);
    if (off > ws_size) return;

    const int NBH = (L_HIST + 1023) / 1024;           // 98
    const int GMM = (N_NODES + 63) / 64;              // 1563 (fc0)
    const int GP  = (N_NODES * 8) / 256;              // 3125 (prop0)
    const int GPC = N_NODES / 32;                     // 3125 (propconv)

    // weight conversion (independent) + CSR bucket-sort build
    k_wcvt<<<45, 256, 0, stream>>>(conv_w, fc1_w, fc0_w, wh, w1h, w0h);
    k_hist<<<256, 256, 0, stream>>>(col, histT);
    k_scanA<<<NBH, 256, 0, stream>>>(histT, hoff, bsum, L_HIST);
    k_scanB<<<1, 128, 0, stream>>>(bsum, NBH);
    k_scanC<<<NBH, 256, 0, stream>>>(hoff, bsum, L_HIST);
    k_scatter1<<<256, 256, 0, stream>>>(row, col, hoff, tmp);
    k_bucket<<<N_BUCKET, 256, 0, stream>>>(tmp, hoff, starts, csr, dinv, rsq);

    // fc0 -> hp0; prop0 -> x0p
    k_fc0<<<GMM, 256, 0, stream>>>(x, w0h, fc0_b, dinv, (uint2*)hp0);
    k_prop0<<<GP, 256, 0, stream>>>(hp0, x0p, dinv, starts, csr);

    const float betas[4] = {0.f, logf(0.5f / 2.f + 1.f), logf(0.5f / 3.f + 1.f), logf(0.5f / 4.f + 1.f)};

    // layer 1: x0p -> hpA ; layer 2: hpA -> hpB ; layer 3 (+fc1): hpB -> d_out
    k_propconv<false><<<GPC, 256, 0, stream>>>(x0p, x0p, dinv, rsq, starts, csr,
                                               wh + 0 * 2048, betas[1], nullptr, nullptr, hpA);
    k_propconv<false><<<GPC, 256, 0, stream>>>(hpA, x0p, dinv, rsq, starts, csr,
                                               wh + 1 * 2048, betas[2], nullptr, nullptr, hpB);
    k_propconv<true><<<GPC, 256, 0, stream>>>(hpB, x0p, dinv, rsq, starts, csr,
                                              wh + 2 * 2048, betas[3], w1h, fc1_b, d_out);
}